// Round 2
// baseline (461.381 us; speedup 1.0000x reference)
//
#include <hip/hip_runtime.h>
#include <hip/hip_bf16.h>

#define NN 100000
#define NE 1200000
#define SCAN_B 256
#define NBLK ((NN + SCAN_B - 1) / SCAN_B)   // 391
#define NE4 (NE / 4)                         // 300000

// ---------------- slot pass: slot[e] = position of edge within its dst bucket; deg counts ----------------
__global__ __launch_bounds__(256) void slot_kernel(const int* __restrict__ dst,
                                                   int* __restrict__ deg,
                                                   int* __restrict__ slot) {
    int i = blockIdx.x * 256 + threadIdx.x;
    if (i < NE4) {
        int4 d = ((const int4*)dst)[i];
        int4 s;
        s.x = atomicAdd(&deg[d.x], 1);
        s.y = atomicAdd(&deg[d.y], 1);
        s.z = atomicAdd(&deg[d.z], 1);
        s.w = atomicAdd(&deg[d.w], 1);
        ((int4*)slot)[i] = s;
    }
}

__global__ __launch_bounds__(256) void dinv_kernel(const int* __restrict__ deg,
                                                   float* __restrict__ dinv) {
    int n = blockIdx.x * 256 + threadIdx.x;
    if (n < NN) dinv[n] = rsqrtf((float)(deg[n] + 1));  // +1 self loop
}

// ---------------- exclusive scan of deg -> rowptr ----------------
__global__ __launch_bounds__(SCAN_B) void scan1_kernel(const int* __restrict__ deg,
                                                       int* __restrict__ rowptr,
                                                       int* __restrict__ bsum) {
    __shared__ int s[SCAN_B];
    int tid = threadIdx.x;
    int n = blockIdx.x * SCAN_B + tid;
    int d = (n < NN) ? deg[n] : 0;
    s[tid] = d;
    for (int off = 1; off < SCAN_B; off <<= 1) {
        __syncthreads();
        int t = (tid >= off) ? s[tid - off] : 0;
        __syncthreads();
        s[tid] += t;
    }
    if (n <= NN) rowptr[n] = s[tid] - d;            // exclusive, partial
    if (tid == SCAN_B - 1) bsum[blockIdx.x] = s[tid];
}

__global__ __launch_bounds__(512) void scan2_kernel(int* __restrict__ bsum,
                                                    int* __restrict__ boff) {
    __shared__ int s[512];
    int tid = threadIdx.x;
    int v = (tid < NBLK) ? bsum[tid] : 0;
    s[tid] = v;
    for (int off = 1; off < 512; off <<= 1) {
        __syncthreads();
        int t = (tid >= off) ? s[tid - off] : 0;
        __syncthreads();
        s[tid] += t;
    }
    if (tid < NBLK) boff[tid] = s[tid] - v;         // exclusive block offsets
}

__global__ __launch_bounds__(SCAN_B) void scan3_kernel(int* __restrict__ rowptr,
                                                       const int* __restrict__ boff) {
    int n = blockIdx.x * SCAN_B + threadIdx.x;
    if (n < NN) rowptr[n] += boff[blockIdx.x];
    if (n == NN - 1) rowptr[NN] = NE;
}

// ---------------- CSR fill (no atomics): csr[rowptr[dst]+slot] = src ----------------
__global__ __launch_bounds__(256) void fill_kernel(const int* __restrict__ src,
                                                   const int* __restrict__ dst,
                                                   const int* __restrict__ slot,
                                                   const int* __restrict__ rowptr,
                                                   int* __restrict__ csr) {
    int i = blockIdx.x * 256 + threadIdx.x;
    if (i < NE4) {
        int4 d  = ((const int4*)dst)[i];
        int4 sl = ((const int4*)slot)[i];
        int4 sr = ((const int4*)src)[i];
        csr[rowptr[d.x] + sl.x] = sr.x;
        csr[rowptr[d.y] + sl.y] = sr.y;
        csr[rowptr[d.z] + sl.z] = sr.z;
        csr[rowptr[d.w] + sl.w] = sr.w;
    }
}

// ---------------- per-node matmul, fused finalize of previous layer ----------------
// MODE 0: v = in[n][f]                          (layer 0 input = x)
// MODE 1: v = relu(dinv[n]*in[n][f]+bias[f])    (finalize of previous conv)
// writes u[n] = bf16( dinv[n] * (v_row @ W) )
template <int MODE>
__global__ __launch_bounds__(256) void mm_kernel(const float* __restrict__ in,
                                                 const float* __restrict__ W,
                                                 const float* __restrict__ bias,
                                                 const float* __restrict__ dinv,
                                                 __hip_bfloat16* __restrict__ u) {
    __shared__ float Ws[64 * 64];
    __shared__ float hrow[4][64];
    int tid = threadIdx.x;
    {   // stage W (16 KB) via float4
        const float4* Wv = (const float4*)W;
        float4* Wsv = (float4*)Ws;
        #pragma unroll
        for (int i = 0; i < 4; ++i) Wsv[tid + 256 * i] = Wv[tid + 256 * i];
    }
    int local = tid >> 6;            // node within block
    int f = tid & 63;                // feature
    int n = blockIdx.x * 4 + local;  // NN divisible by 4
    float din = dinv[n];
    float v = in[n * 64 + f];
    if (MODE == 1) v = fmaxf(fmaf(din, v, bias[f]), 0.f);
    hrow[local][f] = v;
    __syncthreads();
    float acc = 0.f;
    #pragma unroll
    for (int k = 0; k < 64; ++k)
        acc = fmaf(hrow[local][k], Ws[k * 64 + f], acc);
    u[n * 64 + f] = __float2bfloat16(din * acc);
}

// ---------------- high-MLP aggregation core ----------------
// wave = 8 edge-groups x 8 lanes; group handles one edge per sweep, lane covers
// features [fo*8, fo*8+8) via one dwordx4 (16B): a single load instruction puts
// 8 x 128B gathers in flight. CSR row batch-loaded once (coalesced, contiguous)
// and broadcast by shfl. Two leading sweeps fully unrolled into independent
// accumulators -> 16 gathers outstanding before any consume. deg>16 loop is
// ~10% of nodes; deg>64 batch loop is Poisson(12) tail, effectively never.
__device__ __forceinline__ void acc_bf8(float acc[8], uint4 v) {
    acc[0] += __uint_as_float(v.x << 16);
    acc[1] += __uint_as_float(v.x & 0xffff0000u);
    acc[2] += __uint_as_float(v.y << 16);
    acc[3] += __uint_as_float(v.y & 0xffff0000u);
    acc[4] += __uint_as_float(v.z << 16);
    acc[5] += __uint_as_float(v.z & 0xffff0000u);
    acc[6] += __uint_as_float(v.w << 16);
    acc[7] += __uint_as_float(v.w & 0xffff0000u);
}

// On exit: acc[0..8) holds the full aggregated row (self + neighbors) for
// features [fo*8, fo*8+8), replicated across all 8 groups.
__device__ __forceinline__ void agg_row(const int* __restrict__ rowptr,
                                        const int* __restrict__ csr,
                                        const uint4* __restrict__ u4,
                                        int n, int lane, int grp, int fo,
                                        float acc[8]) {
    float acc2[8];
    #pragma unroll
    for (int i = 0; i < 8; ++i) { acc[i] = 0.f; acc2[i] = 0.f; }
    int start = rowptr[n], end = rowptr[n + 1];
    int deg = end - start;
    int cidx = -1;
    if (lane < deg) cidx = csr[start + lane];        // one coalesced row load
    if (grp == 0) acc_bf8(acc, u4[n * 8 + fo]);      // self loop
    int s0 = __shfl(cidx, grp);                      // sweep 0: edges 0..7
    int s1 = __shfl(cidx, grp + 8);                  // sweep 1: edges 8..15
    if (grp < deg) acc_bf8(acc, u4[s0 * 8 + fo]);
    if (grp + 8 < deg) acc_bf8(acc2, u4[s1 * 8 + fo]);
    int dcap = deg < 64 ? deg : 64;
    for (int j = grp + 16; j < dcap; j += 8) {       // deg in (16,64]
        int s = __shfl(cidx, j);
        acc_bf8(acc, u4[s * 8 + fo]);
    }
    for (int base = start + 64; base < end; base += 64) {  // deg > 64: ~never
        int bcnt = end - base; if (bcnt > 64) bcnt = 64;
        int c2 = (lane < bcnt) ? csr[base + lane] : -1;
        for (int j = grp; j < bcnt; j += 8) {
            int s = __shfl(c2, j);
            acc_bf8(acc2, u4[s * 8 + fo]);
        }
    }
    #pragma unroll
    for (int i = 0; i < 8; ++i) {                    // merge sweeps + 8 groups
        float v = acc[i] + acc2[i];
        v += __shfl_xor(v, 8);
        v += __shfl_xor(v, 16);
        v += __shfl_xor(v, 32);
        acc[i] = v;
    }
}

// ---------------- aggregate: a[n][:] = u[n] + sum_{e in in(n)} u[csr[e]] ----------------
// one wave per node, 100000 waves: max TLP, no epilogue beyond a 256B store.
__global__ __launch_bounds__(256) void agg_kernel(const int* __restrict__ rowptr,
                                                  const int* __restrict__ csr,
                                                  const uint4* __restrict__ uin,
                                                  float* __restrict__ a) {
    int tid = threadIdx.x;
    int lane = tid & 63;
    int grp = lane >> 3;
    int fo = lane & 7;
    int n = blockIdx.x * 4 + (tid >> 6);             // NN divisible by 4
    float acc[8];
    agg_row(rowptr, csr, uin, n, lane, grp, fo, acc);
    if (lane < 16) {                                 // 16 lanes x float4 = 256B/node
        float4 v = (lane < 8) ? make_float4(acc[0], acc[1], acc[2], acc[3])
                              : make_float4(acc[4], acc[5], acc[6], acc[7]);
        ((float4*)a)[n * 16 + (lane & 7) * 2 + (lane >> 3)] = v;
    }
}

// ---------------- fused final aggregate + pool: g[f] += sum_n dinv[n]*agg[n][f] ----------------
__global__ __launch_bounds__(256) void aggpool_kernel(const int* __restrict__ rowptr,
                                                      const int* __restrict__ csr,
                                                      const uint4* __restrict__ uin,
                                                      const float* __restrict__ dinv,
                                                      float* __restrict__ gsum) {
    __shared__ float gpart[64];
    int tid = threadIdx.x;
    if (tid < 64) gpart[tid] = 0.f;
    __syncthreads();
    int wid = tid >> 6;
    int lane = tid & 63;
    int grp = lane >> 3;
    int fo = lane & 7;
    float pacc[8];
    #pragma unroll
    for (int i = 0; i < 8; ++i) pacc[i] = 0.f;
    for (int n = blockIdx.x * 4 + wid; n < NN; n += gridDim.x * 4) {
        float acc[8];
        agg_row(rowptr, csr, uin, n, lane, grp, fo, acc);
        float din = dinv[n];
        #pragma unroll
        for (int i = 0; i < 8; ++i) pacc[i] = fmaf(din, acc[i], pacc[i]);
    }
    if (grp == 0) {                                   // values replicated across groups
        #pragma unroll
        for (int i = 0; i < 8; ++i) atomicAdd(&gpart[fo * 8 + i], pacc[i]);
    }
    __syncthreads();
    if (tid < 64) atomicAdd(&gsum[tid], gpart[tid]);
}

// ---------------- head: out = (g + N*b2) @ Wl + bl ----------------
__global__ __launch_bounds__(64) void head_kernel(const float* __restrict__ g,
                                                  const float* __restrict__ b2,
                                                  const float* __restrict__ Wl,
                                                  const float* __restrict__ bl,
                                                  float* __restrict__ out) {
    int t = threadIdx.x;  // one wave
    float gf = g[t] + (float)NN * b2[t];
    #pragma unroll
    for (int c = 0; c < 10; ++c) {
        float p = gf * Wl[t * 10 + c];
        #pragma unroll
        for (int off = 32; off > 0; off >>= 1) p += __shfl_down(p, off);
        if (t == 0) out[c] = p + bl[c];
    }
}

extern "C" void kernel_launch(void* const* d_in, const int* in_sizes, int n_in,
                              void* d_out, int out_size, void* d_ws, size_t ws_size,
                              hipStream_t stream) {
    const float* x  = (const float*)d_in[0];
    const int* eidx = (const int*)d_in[1];
    const int* esrc = eidx;        // edge_idx[0]
    const int* edst = eidx + NE;   // edge_idx[1]
    const float* W0 = (const float*)d_in[2];
    const float* b0 = (const float*)d_in[3];
    const float* W1 = (const float*)d_in[4];
    const float* b1 = (const float*)d_in[5];
    const float* W2 = (const float*)d_in[6];
    const float* b2 = (const float*)d_in[7];
    const float* Wl = (const float*)d_in[8];
    const float* bl = (const float*)d_in[9];
    float* out = (float*)d_out;

    // workspace layout (4-byte units); u and a are 16B-aligned
    float* ws = (float*)d_ws;
    size_t off = 0;
    int*   deg    = (int*)(ws + off); off += NN;
    float* dinv   =        ws + off;  off += NN;
    __hip_bfloat16* u = (__hip_bfloat16*)(ws + off); off += (size_t)NN * 32;  // bf16 N*64
    float* a      =        ws + off;  off += (size_t)NN * 64;
    float* g      =        ws + off;  off += 64;
    int*   rowptr = (int*)(ws + off); off += NN + 1;
    int*   slot   = (int*)(ws + off); off += NE;
    int*   bsum   = (int*)(ws + off); off += 512;
    int*   boff   = (int*)(ws + off); off += 512;
    int*   csr    = (int*)(ws + off); off += NE;

    hipMemsetAsync(deg, 0, NN * sizeof(int), stream);
    hipMemsetAsync(g, 0, 64 * sizeof(float), stream);

    // norm + CSR build (once; reused by all 3 layers)
    slot_kernel<<<(NE4 + 255) / 256, 256, 0, stream>>>(edst, deg, slot);
    dinv_kernel<<<(NN + 255) / 256, 256, 0, stream>>>(deg, dinv);
    scan1_kernel<<<NBLK, SCAN_B, 0, stream>>>(deg, rowptr, bsum);
    scan2_kernel<<<1, 512, 0, stream>>>(bsum, boff);
    scan3_kernel<<<NBLK, SCAN_B, 0, stream>>>(rowptr, boff);
    fill_kernel<<<(NE4 + 255) / 256, 256, 0, stream>>>(esrc, edst, slot, rowptr, csr);

    // layer 0
    mm_kernel<0><<<NN / 4, 256, 0, stream>>>(x, W0, nullptr, dinv, u);
    agg_kernel<<<NN / 4, 256, 0, stream>>>(rowptr, csr, (const uint4*)u, a);
    // layer 1
    mm_kernel<1><<<NN / 4, 256, 0, stream>>>(a, W1, b0, dinv, u);
    agg_kernel<<<NN / 4, 256, 0, stream>>>(rowptr, csr, (const uint4*)u, a);
    // layer 2
    mm_kernel<1><<<NN / 4, 256, 0, stream>>>(a, W2, b1, dinv, u);
    // fused: agg(layer2) + pool (dinv folded; N*b2 added in head)
    aggpool_kernel<<<NN / 16, 256, 0, stream>>>(rowptr, csr, (const uint4*)u, dinv, g);
    head_kernel<<<1, 64, 0, stream>>>(g, b2, Wl, bl, out);
}

// Round 3
// 453.343 us; speedup vs baseline: 1.0177x; 1.0177x over previous
//
#include <hip/hip_runtime.h>
#include <hip/hip_bf16.h>

#define NN 100000
#define NE 1200000
#define SCAN_B 256
#define NBLK ((NN + SCAN_B - 1) / SCAN_B)   // 391
#define NE4 (NE / 4)                         // 300000

// ---------------- count pass: deg[d]++ (non-returning atomics: no vmcnt dependency) ----------------
__global__ __launch_bounds__(256) void count_kernel(const int* __restrict__ dst,
                                                    int* __restrict__ deg) {
    int i = blockIdx.x * 256 + threadIdx.x;
    if (i < NE4) {
        int4 d = ((const int4*)dst)[i];
        atomicAdd(&deg[d.x], 1);
        atomicAdd(&deg[d.y], 1);
        atomicAdd(&deg[d.z], 1);
        atomicAdd(&deg[d.w], 1);
    }
}

// ---------------- exclusive scan of deg -> rowptr (+ fused dinv) ----------------
__global__ __launch_bounds__(SCAN_B) void scan1_kernel(const int* __restrict__ deg,
                                                       int* __restrict__ rowptr,
                                                       int* __restrict__ bsum,
                                                       float* __restrict__ dinv) {
    __shared__ int s[SCAN_B];
    int tid = threadIdx.x;
    int n = blockIdx.x * SCAN_B + tid;
    int d = (n < NN) ? deg[n] : 0;
    if (n < NN) dinv[n] = rsqrtf((float)(d + 1));   // +1 self loop
    s[tid] = d;
    for (int off = 1; off < SCAN_B; off <<= 1) {
        __syncthreads();
        int t = (tid >= off) ? s[tid - off] : 0;
        __syncthreads();
        s[tid] += t;
    }
    if (n <= NN) rowptr[n] = s[tid] - d;            // exclusive, partial
    if (tid == SCAN_B - 1) bsum[blockIdx.x] = s[tid];
}

__global__ __launch_bounds__(512) void scan2_kernel(int* __restrict__ bsum,
                                                    int* __restrict__ boff) {
    __shared__ int s[512];
    int tid = threadIdx.x;
    int v = (tid < NBLK) ? bsum[tid] : 0;
    s[tid] = v;
    for (int off = 1; off < 512; off <<= 1) {
        __syncthreads();
        int t = (tid >= off) ? s[tid - off] : 0;
        __syncthreads();
        s[tid] += t;
    }
    if (tid < NBLK) boff[tid] = s[tid] - v;         // exclusive block offsets
}

// finalize rowptr and write the fill cursor copy rp2
__global__ __launch_bounds__(SCAN_B) void scan3_kernel(int* __restrict__ rowptr,
                                                       const int* __restrict__ boff,
                                                       int* __restrict__ rp2) {
    int n = blockIdx.x * SCAN_B + threadIdx.x;
    if (n < NN) {
        int v = rowptr[n] + boff[blockIdx.x];
        rowptr[n] = v;
        rp2[n] = v;
    }
    if (n == NN - 1) rowptr[NN] = NE;
}

// ---------------- CSR fill: position via atomic cursor (order within row is arbitrary) ----------------
__global__ __launch_bounds__(256) void fill_kernel(const int* __restrict__ src,
                                                   const int* __restrict__ dst,
                                                   int* __restrict__ rp2,
                                                   int* __restrict__ csr) {
    int i = blockIdx.x * 256 + threadIdx.x;
    if (i < NE4) {
        int4 d  = ((const int4*)dst)[i];
        int4 sr = ((const int4*)src)[i];
        int px = atomicAdd(&rp2[d.x], 1);
        int py = atomicAdd(&rp2[d.y], 1);
        int pz = atomicAdd(&rp2[d.z], 1);
        int pw = atomicAdd(&rp2[d.w], 1);
        csr[px] = sr.x;
        csr[py] = sr.y;
        csr[pz] = sr.z;
        csr[pw] = sr.w;
    }
}

// ---------------- per-node matmul, fused finalize of previous layer ----------------
// MODE 0: v = in[n][f]                          (layer 0 input = x)
// MODE 1: v = relu(dinv[n]*in[n][f]+bias[f])    (finalize of previous conv)
// writes u[n] = bf16( dinv[n] * (v_row @ W) )
template <int MODE>
__global__ __launch_bounds__(256) void mm_kernel(const float* __restrict__ in,
                                                 const float* __restrict__ W,
                                                 const float* __restrict__ bias,
                                                 const float* __restrict__ dinv,
                                                 __hip_bfloat16* __restrict__ u) {
    __shared__ float Ws[64 * 64];
    __shared__ float hrow[4][64];
    int tid = threadIdx.x;
    {   // stage W (16 KB) via float4 (broadcast reads: keep cached)
        const float4* Wv = (const float4*)W;
        float4* Wsv = (float4*)Ws;
        #pragma unroll
        for (int i = 0; i < 4; ++i) Wsv[tid + 256 * i] = Wv[tid + 256 * i];
    }
    int local = tid >> 6;            // node within block
    int f = tid & 63;                // feature
    int n = blockIdx.x * 4 + local;  // NN divisible by 4
    float din = dinv[n];
    float v = __builtin_nontemporal_load(&in[n * 64 + f]);  // read-once stream: don't evict u
    if (MODE == 1) v = fmaxf(fmaf(din, v, bias[f]), 0.f);
    hrow[local][f] = v;
    __syncthreads();
    float acc = 0.f;
    #pragma unroll
    for (int k = 0; k < 64; ++k)
        acc = fmaf(hrow[local][k], Ws[k * 64 + f], acc);
    u[n * 64 + f] = __float2bfloat16(din * acc);
}

// ---------------- aggregation core, G=4 ----------------
// wave = 4 edge-groups x 16 lanes; lane covers features [fp*4, fp*4+4) via one
// dwordx2 (8B): 16 lanes span the whole 128B u-row. CSR row batch-loaded once
// (coalesced, nontemporal) and broadcast by shfl. 4 sweeps fully unrolled into
// independent accumulators (deg<=16 covers ~90% of Poisson(12) nodes).
// Reduce tail: 2 shfl_xor levels x 4 values (vs 3 levels x 8 at G=8).
__device__ __forceinline__ void acc_bf4(float acc[4], uint2 v) {
    acc[0] += __uint_as_float(v.x << 16);
    acc[1] += __uint_as_float(v.x & 0xffff0000u);
    acc[2] += __uint_as_float(v.y << 16);
    acc[3] += __uint_as_float(v.y & 0xffff0000u);
}

// On exit: acc[0..4) = aggregated row (self + neighbors) for features
// [fp*4, fp*4+4), replicated across the 4 groups.
__device__ __forceinline__ void agg_row(const int* __restrict__ rowptr,
                                        const int* __restrict__ csr,
                                        const uint2* __restrict__ u2,
                                        int n, int lane, int grp, int fp,
                                        float acc[4]) {
    float a0[4], a1[4], a2[4], a3[4];
    #pragma unroll
    for (int i = 0; i < 4; ++i) { a0[i] = 0.f; a1[i] = 0.f; a2[i] = 0.f; a3[i] = 0.f; }
    int start = rowptr[n], end = rowptr[n + 1];
    int deg = end - start;
    int cidx = -1;
    if (lane < deg) cidx = __builtin_nontemporal_load(&csr[start + lane]); // read-once stream
    if (grp == 0) acc_bf4(a0, u2[n * 16 + fp]);       // self loop
    int s0 = __shfl(cidx, grp);                       // edges 0..3
    int s1 = __shfl(cidx, grp + 4);                   // edges 4..7
    int s2 = __shfl(cidx, grp + 8);                   // edges 8..11
    int s3 = __shfl(cidx, grp + 12);                  // edges 12..15
    if (grp < deg)      acc_bf4(a0, u2[s0 * 16 + fp]);
    if (grp + 4 < deg)  acc_bf4(a1, u2[s1 * 16 + fp]);
    if (grp + 8 < deg)  acc_bf4(a2, u2[s2 * 16 + fp]);
    if (grp + 12 < deg) acc_bf4(a3, u2[s3 * 16 + fp]);
    int dcap = deg < 64 ? deg : 64;
    for (int j = grp + 16; j < dcap; j += 4) {        // deg in (16,64]
        int s = __shfl(cidx, j);
        acc_bf4(a1, u2[s * 16 + fp]);
    }
    for (int base = start + 64; base < end; base += 64) {  // deg > 64: ~never
        int bcnt = end - base; if (bcnt > 64) bcnt = 64;
        int c2 = (lane < bcnt) ? __builtin_nontemporal_load(&csr[base + lane]) : -1;
        for (int j = grp; j < bcnt; j += 4) {
            int s = __shfl(c2, j);
            acc_bf4(a2, u2[s * 16 + fp]);
        }
    }
    #pragma unroll
    for (int i = 0; i < 4; ++i) {                     // merge sweeps + 4 groups
        float v = (a0[i] + a1[i]) + (a2[i] + a3[i]);
        v += __shfl_xor(v, 16);
        v += __shfl_xor(v, 32);
        acc[i] = v;
    }
}

// ---------------- aggregate (POOL=0: a[n][:]=agg; POOL=1: fused global pool) ----------------
// one wave per node, 100000 waves: max TLP. POOL=1 accumulates dinv[n]*agg into
// per-block LDS partials, flushed to 64-way-spread global partials gp[64][64].
template <int POOL>
__global__ __launch_bounds__(256) void agg_kernel(const int* __restrict__ rowptr,
                                                  const int* __restrict__ csr,
                                                  const uint2* __restrict__ uin,
                                                  const float* __restrict__ dinv,
                                                  float* __restrict__ a,
                                                  float* __restrict__ gp) {
    __shared__ float gpart[64];
    int tid = threadIdx.x;
    if (POOL) {
        if (tid < 64) gpart[tid] = 0.f;
        __syncthreads();
    }
    int lane = tid & 63;
    int grp = lane >> 4;
    int fp = lane & 15;
    int n = blockIdx.x * 4 + (tid >> 6);              // NN divisible by 4
    float acc[4];
    agg_row(rowptr, csr, uin, n, lane, grp, fp, acc);
    if (POOL) {
        if (grp == 0) {                               // lanes 0..15 hold the full row
            float din = dinv[n];
            #pragma unroll
            for (int i = 0; i < 4; ++i) atomicAdd(&gpart[fp * 4 + i], din * acc[i]);
        }
        __syncthreads();
        if (tid < 64) atomicAdd(&gp[(blockIdx.x & 63) * 64 + tid], gpart[tid]);
    } else {
        if (lane < 16)                                // 16 lanes x float4 = the 256B row
            ((float4*)a)[n * 16 + fp] = make_float4(acc[0], acc[1], acc[2], acc[3]);
    }
}

// ---------------- head: g = colsum(gp) + N*b2;  out = g @ Wl + bl ----------------
__global__ __launch_bounds__(64) void head_kernel(const float* __restrict__ gp,
                                                  const float* __restrict__ b2,
                                                  const float* __restrict__ Wl,
                                                  const float* __restrict__ bl,
                                                  float* __restrict__ out) {
    int t = threadIdx.x;  // one wave
    float s = 0.f;
    #pragma unroll 8
    for (int r = 0; r < 64; ++r) s += gp[r * 64 + t];
    float gf = s + (float)NN * b2[t];
    #pragma unroll
    for (int c = 0; c < 10; ++c) {
        float p = gf * Wl[t * 10 + c];
        #pragma unroll
        for (int off = 32; off > 0; off >>= 1) p += __shfl_down(p, off);
        if (t == 0) out[c] = p + bl[c];
    }
}

extern "C" void kernel_launch(void* const* d_in, const int* in_sizes, int n_in,
                              void* d_out, int out_size, void* d_ws, size_t ws_size,
                              hipStream_t stream) {
    const float* x  = (const float*)d_in[0];
    const int* eidx = (const int*)d_in[1];
    const int* esrc = eidx;        // edge_idx[0]
    const int* edst = eidx + NE;   // edge_idx[1]
    const float* W0 = (const float*)d_in[2];
    const float* b0 = (const float*)d_in[3];
    const float* W1 = (const float*)d_in[4];
    const float* b1 = (const float*)d_in[5];
    const float* W2 = (const float*)d_in[6];
    const float* b2 = (const float*)d_in[7];
    const float* Wl = (const float*)d_in[8];
    const float* bl = (const float*)d_in[9];
    float* out = (float*)d_out;

    // workspace layout (4-byte units); u and a are 16B-aligned
    float* ws = (float*)d_ws;
    size_t off = 0;
    int*   deg    = (int*)(ws + off); off += NN;
    float* dinv   =        ws + off;  off += NN;
    __hip_bfloat16* u = (__hip_bfloat16*)(ws + off); off += (size_t)NN * 32;  // bf16 N*64
    float* a      =        ws + off;  off += (size_t)NN * 64;
    float* gp     =        ws + off;  off += 64 * 64;   // pool partials
    int*   rowptr = (int*)(ws + off); off += NN + 1;
    int*   rp2    = (int*)(ws + off); off += NN;
    int*   bsum   = (int*)(ws + off); off += 512;
    int*   boff   = (int*)(ws + off); off += 512;
    int*   csr    = (int*)(ws + off); off += NE;

    hipMemsetAsync(deg, 0, NN * sizeof(int), stream);
    hipMemsetAsync(gp, 0, 64 * 64 * sizeof(float), stream);

    // norm + CSR build (once; reused by all 3 layers)
    count_kernel<<<(NE4 + 255) / 256, 256, 0, stream>>>(edst, deg);
    scan1_kernel<<<NBLK, SCAN_B, 0, stream>>>(deg, rowptr, bsum, dinv);
    scan2_kernel<<<1, 512, 0, stream>>>(bsum, boff);
    scan3_kernel<<<NBLK, SCAN_B, 0, stream>>>(rowptr, boff, rp2);
    fill_kernel<<<(NE4 + 255) / 256, 256, 0, stream>>>(esrc, edst, rp2, csr);

    // layer 0
    mm_kernel<0><<<NN / 4, 256, 0, stream>>>(x, W0, nullptr, dinv, u);
    agg_kernel<0><<<NN / 4, 256, 0, stream>>>(rowptr, csr, (const uint2*)u, dinv, a, gp);
    // layer 1
    mm_kernel<1><<<NN / 4, 256, 0, stream>>>(a, W1, b0, dinv, u);
    agg_kernel<0><<<NN / 4, 256, 0, stream>>>(rowptr, csr, (const uint2*)u, dinv, a, gp);
    // layer 2
    mm_kernel<1><<<NN / 4, 256, 0, stream>>>(a, W2, b1, dinv, u);
    // fused: agg(layer2) + global pool (dinv folded; N*b2 added in head)
    agg_kernel<1><<<NN / 4, 256, 0, stream>>>(rowptr, csr, (const uint2*)u, dinv, a, gp);
    head_kernel<<<1, 64, 0, stream>>>(gp, b2, Wl, bl, out);
}

// Round 4
// 400.454 us; speedup vs baseline: 1.1521x; 1.1321x over previous
//
#include <hip/hip_runtime.h>
#include <hip/hip_bf16.h>

#define NN 100000
#define NE 1200000
#define SCAN_B 256
#define NBLK ((NN + SCAN_B - 1) / SCAN_B)   // 391
#define NE4 (NE / 4)                         // 300000
#define XCD_N 8
#define NPX (NN / XCD_N)                     // 12500 nodes per XCD

// ---------------- count pass, XCD-partitioned ----------------
// block b (XCD = b&7) stripes the full edge list with its XCD's sibling blocks
// and counts only dsts in its XCD's node range: deg/cursor lines are touched by
// exactly one XCD -> L2-local atomics, no cross-XCD line ping-pong.
__global__ __launch_bounds__(256) void count_kernel(const int* __restrict__ dst,
                                                    int* __restrict__ deg) {
    int xcd = blockIdx.x & 7;
    int sub = blockIdx.x >> 3;
    int nsub = gridDim.x >> 3;
    int lo = xcd * NPX;
    for (int i = sub * 256 + threadIdx.x; i < NE4; i += nsub * 256) {
        int4 d = ((const int4*)dst)[i];
        if ((unsigned)(d.x - lo) < NPX) atomicAdd(&deg[d.x], 1);
        if ((unsigned)(d.y - lo) < NPX) atomicAdd(&deg[d.y], 1);
        if ((unsigned)(d.z - lo) < NPX) atomicAdd(&deg[d.z], 1);
        if ((unsigned)(d.w - lo) < NPX) atomicAdd(&deg[d.w], 1);
    }
}

// ---------------- exclusive scan of deg -> rowptr (+ fused dinv) ----------------
__global__ __launch_bounds__(SCAN_B) void scan1_kernel(const int* __restrict__ deg,
                                                       int* __restrict__ rowptr,
                                                       int* __restrict__ bsum,
                                                       float* __restrict__ dinv) {
    __shared__ int s[SCAN_B];
    int tid = threadIdx.x;
    int n = blockIdx.x * SCAN_B + tid;
    int d = (n < NN) ? deg[n] : 0;
    if (n < NN) dinv[n] = rsqrtf((float)(d + 1));   // +1 self loop
    s[tid] = d;
    for (int off = 1; off < SCAN_B; off <<= 1) {
        __syncthreads();
        int t = (tid >= off) ? s[tid - off] : 0;
        __syncthreads();
        s[tid] += t;
    }
    if (n <= NN) rowptr[n] = s[tid] - d;            // exclusive, partial
    if (tid == SCAN_B - 1) bsum[blockIdx.x] = s[tid];
}

__global__ __launch_bounds__(512) void scan2_kernel(int* __restrict__ bsum,
                                                    int* __restrict__ boff) {
    __shared__ int s[512];
    int tid = threadIdx.x;
    int v = (tid < NBLK) ? bsum[tid] : 0;
    s[tid] = v;
    for (int off = 1; off < 512; off <<= 1) {
        __syncthreads();
        int t = (tid >= off) ? s[tid - off] : 0;
        __syncthreads();
        s[tid] += t;
    }
    if (tid < NBLK) boff[tid] = s[tid] - v;         // exclusive block offsets
}

// finalize rowptr and write the fill cursor copy rp2
__global__ __launch_bounds__(SCAN_B) void scan3_kernel(int* __restrict__ rowptr,
                                                       const int* __restrict__ boff,
                                                       int* __restrict__ rp2) {
    int n = blockIdx.x * SCAN_B + threadIdx.x;
    if (n < NN) {
        int v = rowptr[n] + boff[blockIdx.x];
        rowptr[n] = v;
        rp2[n] = v;
    }
    if (n == NN - 1) rowptr[NN] = NE;
}

// ---------------- CSR fill, XCD-partitioned ----------------
// same ownership scheme as count: each csr line is written by one XCD only ->
// dirty lines accumulate all their edges in that XCD's L2 and evict once
// (R3 showed 85 MB HBM writes for 4.8 MB of payload without this).
__global__ __launch_bounds__(256) void fill_kernel(const int* __restrict__ src,
                                                   const int* __restrict__ dst,
                                                   int* __restrict__ rp2,
                                                   int* __restrict__ csr) {
    int xcd = blockIdx.x & 7;
    int sub = blockIdx.x >> 3;
    int nsub = gridDim.x >> 3;
    int lo = xcd * NPX;
    for (int i = sub * 256 + threadIdx.x; i < NE4; i += nsub * 256) {
        int4 d  = ((const int4*)dst)[i];
        int4 sr = ((const int4*)src)[i];
        if ((unsigned)(d.x - lo) < NPX) { int p = atomicAdd(&rp2[d.x], 1); csr[p] = sr.x; }
        if ((unsigned)(d.y - lo) < NPX) { int p = atomicAdd(&rp2[d.y], 1); csr[p] = sr.y; }
        if ((unsigned)(d.z - lo) < NPX) { int p = atomicAdd(&rp2[d.z], 1); csr[p] = sr.z; }
        if ((unsigned)(d.w - lo) < NPX) { int p = atomicAdd(&rp2[d.w], 1); csr[p] = sr.w; }
    }
}

// ---------------- per-node matmul, fused finalize of previous layer ----------------
// MODE 0: v = in[n][f]                          (layer 0 input = x)
// MODE 1: v = relu(dinv[n]*in[n][f]+bias[f])    (finalize of previous conv)
// writes u[n] = bf16( dinv[n] * (v_row @ W) )
template <int MODE>
__global__ __launch_bounds__(256) void mm_kernel(const float* __restrict__ in,
                                                 const float* __restrict__ W,
                                                 const float* __restrict__ bias,
                                                 const float* __restrict__ dinv,
                                                 __hip_bfloat16* __restrict__ u) {
    __shared__ float Ws[64 * 64];
    __shared__ float hrow[4][64];
    int tid = threadIdx.x;
    {   // stage W (16 KB) via float4
        const float4* Wv = (const float4*)W;
        float4* Wsv = (float4*)Ws;
        #pragma unroll
        for (int i = 0; i < 4; ++i) Wsv[tid + 256 * i] = Wv[tid + 256 * i];
    }
    int local = tid >> 6;            // node within block
    int f = tid & 63;                // feature
    int n = blockIdx.x * 4 + local;  // NN divisible by 4
    float din = dinv[n];
    float v = in[n * 64 + f];
    if (MODE == 1) v = fmaxf(fmaf(din, v, bias[f]), 0.f);
    hrow[local][f] = v;
    __syncthreads();
    float acc = 0.f;
    #pragma unroll
    for (int k = 0; k < 64; ++k)
        acc = fmaf(hrow[local][k], Ws[k * 64 + f], acc);
    u[n * 64 + f] = __float2bfloat16(din * acc);
}

// ---------------- aggregation core, G=8 (proven ~56us/layer in R2) ----------------
// wave = 8 edge-groups x 8 lanes; group handles one edge per sweep, lane covers
// features [fo*8, fo*8+8) via one dwordx4 (16B): one load instruction = 8 x 128B
// gathers in flight. CSR row batch-loaded once (coalesced, NORMAL load: it is on
// the serial head of the chain and reused across 3 layers - R3's nontemporal
// variant regressed). Two leading sweeps unrolled into independent accumulators.
__device__ __forceinline__ void acc_bf8(float acc[8], uint4 v) {
    acc[0] += __uint_as_float(v.x << 16);
    acc[1] += __uint_as_float(v.x & 0xffff0000u);
    acc[2] += __uint_as_float(v.y << 16);
    acc[3] += __uint_as_float(v.y & 0xffff0000u);
    acc[4] += __uint_as_float(v.z << 16);
    acc[5] += __uint_as_float(v.z & 0xffff0000u);
    acc[6] += __uint_as_float(v.w << 16);
    acc[7] += __uint_as_float(v.w & 0xffff0000u);
}

// On exit: acc[0..8) = aggregated row (self + neighbors) for features
// [fo*8, fo*8+8), replicated across the 8 groups.
__device__ __forceinline__ void agg_row(const int* __restrict__ rowptr,
                                        const int* __restrict__ csr,
                                        const uint4* __restrict__ u4,
                                        int n, int lane, int grp, int fo,
                                        float acc[8]) {
    float acc2[8];
    #pragma unroll
    for (int i = 0; i < 8; ++i) { acc[i] = 0.f; acc2[i] = 0.f; }
    int start = rowptr[n], end = rowptr[n + 1];
    int deg = end - start;
    int cidx = -1;
    if (lane < deg) cidx = csr[start + lane];        // one coalesced row load
    if (grp == 0) acc_bf8(acc, u4[n * 8 + fo]);      // self loop
    int s0 = __shfl(cidx, grp);                      // sweep 0: edges 0..7
    int s1 = __shfl(cidx, grp + 8);                  // sweep 1: edges 8..15
    if (grp < deg) acc_bf8(acc, u4[s0 * 8 + fo]);
    if (grp + 8 < deg) acc_bf8(acc2, u4[s1 * 8 + fo]);
    int dcap = deg < 64 ? deg : 64;
    for (int j = grp + 16; j < dcap; j += 8) {       // deg in (16,64]
        int s = __shfl(cidx, j);
        acc_bf8(acc, u4[s * 8 + fo]);
    }
    for (int base = start + 64; base < end; base += 64) {  // deg > 64: ~never
        int bcnt = end - base; if (bcnt > 64) bcnt = 64;
        int c2 = (lane < bcnt) ? csr[base + lane] : -1;
        for (int j = grp; j < bcnt; j += 8) {
            int s = __shfl(c2, j);
            acc_bf8(acc2, u4[s * 8 + fo]);
        }
    }
    #pragma unroll
    for (int i = 0; i < 8; ++i) {                    // merge sweeps + 8 groups
        float v = acc[i] + acc2[i];
        v += __shfl_xor(v, 8);
        v += __shfl_xor(v, 16);
        v += __shfl_xor(v, 32);
        acc[i] = v;
    }
}

// ---------------- aggregate (POOL=0: a[n][:]=agg; POOL=1: fused global pool) ----------------
// one wave per node, 100000 waves: max TLP, no serial nodes (R1/R2 lesson).
template <int POOL>
__global__ __launch_bounds__(256) void agg_kernel(const int* __restrict__ rowptr,
                                                  const int* __restrict__ csr,
                                                  const uint4* __restrict__ uin,
                                                  const float* __restrict__ dinv,
                                                  float* __restrict__ a,
                                                  float* __restrict__ gp) {
    __shared__ float gpart[64];
    int tid = threadIdx.x;
    if (POOL) {
        if (tid < 64) gpart[tid] = 0.f;
        __syncthreads();
    }
    int lane = tid & 63;
    int grp = lane >> 3;
    int fo = lane & 7;
    int n = blockIdx.x * 4 + (tid >> 6);              // NN divisible by 4
    float acc[8];
    agg_row(rowptr, csr, uin, n, lane, grp, fo, acc);
    if (POOL) {
        if (grp == 0) {                               // lanes 0..7 hold the full row
            float din = dinv[n];
            #pragma unroll
            for (int i = 0; i < 8; ++i) atomicAdd(&gpart[fo * 8 + i], din * acc[i]);
        }
        __syncthreads();
        if (tid < 64) atomicAdd(&gp[(blockIdx.x & 63) * 64 + tid], gpart[tid]);
    } else {
        if (lane < 16) {                              // 16 lanes x float4 = the 256B row
            float4 v = (lane < 8) ? make_float4(acc[0], acc[1], acc[2], acc[3])
                                  : make_float4(acc[4], acc[5], acc[6], acc[7]);
            ((float4*)a)[n * 16 + (lane & 7) * 2 + (lane >> 3)] = v;
        }
    }
}

// ---------------- head: g = colsum(gp) + N*b2;  out = g @ Wl + bl ----------------
__global__ __launch_bounds__(64) void head_kernel(const float* __restrict__ gp,
                                                  const float* __restrict__ b2,
                                                  const float* __restrict__ Wl,
                                                  const float* __restrict__ bl,
                                                  float* __restrict__ out) {
    int t = threadIdx.x;  // one wave
    float s = 0.f;
    #pragma unroll 8
    for (int r = 0; r < 64; ++r) s += gp[r * 64 + t];
    float gf = s + (float)NN * b2[t];
    #pragma unroll
    for (int c = 0; c < 10; ++c) {
        float p = gf * Wl[t * 10 + c];
        #pragma unroll
        for (int off = 32; off > 0; off >>= 1) p += __shfl_down(p, off);
        if (t == 0) out[c] = p + bl[c];
    }
}

extern "C" void kernel_launch(void* const* d_in, const int* in_sizes, int n_in,
                              void* d_out, int out_size, void* d_ws, size_t ws_size,
                              hipStream_t stream) {
    const float* x  = (const float*)d_in[0];
    const int* eidx = (const int*)d_in[1];
    const int* esrc = eidx;        // edge_idx[0]
    const int* edst = eidx + NE;   // edge_idx[1]
    const float* W0 = (const float*)d_in[2];
    const float* b0 = (const float*)d_in[3];
    const float* W1 = (const float*)d_in[4];
    const float* b1 = (const float*)d_in[5];
    const float* W2 = (const float*)d_in[6];
    const float* b2 = (const float*)d_in[7];
    const float* Wl = (const float*)d_in[8];
    const float* bl = (const float*)d_in[9];
    float* out = (float*)d_out;

    // workspace layout (4-byte units); u and a are 16B-aligned
    float* ws = (float*)d_ws;
    size_t off = 0;
    int*   deg    = (int*)(ws + off); off += NN;
    float* dinv   =        ws + off;  off += NN;
    __hip_bfloat16* u = (__hip_bfloat16*)(ws + off); off += (size_t)NN * 32;  // bf16 N*64
    float* a      =        ws + off;  off += (size_t)NN * 64;
    float* gp     =        ws + off;  off += 64 * 64;   // pool partials
    int*   rowptr = (int*)(ws + off); off += NN + 1;
    int*   rp2    = (int*)(ws + off); off += NN;
    int*   bsum   = (int*)(ws + off); off += 512;
    int*   boff   = (int*)(ws + off); off += 512;
    int*   csr    = (int*)(ws + off); off += NE;

    hipMemsetAsync(deg, 0, NN * sizeof(int), stream);
    hipMemsetAsync(gp, 0, 64 * 64 * sizeof(float), stream);

    // norm + CSR build (once; reused by all 3 layers)
    count_kernel<<<2048, 256, 0, stream>>>(edst, deg);
    scan1_kernel<<<NBLK, SCAN_B, 0, stream>>>(deg, rowptr, bsum, dinv);
    scan2_kernel<<<1, 512, 0, stream>>>(bsum, boff);
    scan3_kernel<<<NBLK, SCAN_B, 0, stream>>>(rowptr, boff, rp2);
    fill_kernel<<<2048, 256, 0, stream>>>(esrc, edst, rp2, csr);

    // layer 0
    mm_kernel<0><<<NN / 4, 256, 0, stream>>>(x, W0, nullptr, dinv, u);
    agg_kernel<0><<<NN / 4, 256, 0, stream>>>(rowptr, csr, (const uint4*)u, dinv, a, gp);
    // layer 1
    mm_kernel<1><<<NN / 4, 256, 0, stream>>>(a, W1, b0, dinv, u);
    agg_kernel<0><<<NN / 4, 256, 0, stream>>>(rowptr, csr, (const uint4*)u, dinv, a, gp);
    // layer 2
    mm_kernel<1><<<NN / 4, 256, 0, stream>>>(a, W2, b1, dinv, u);
    // fused: agg(layer2) + global pool (dinv folded; N*b2 added in head)
    agg_kernel<1><<<NN / 4, 256, 0, stream>>>(rowptr, csr, (const uint4*)u, dinv, a, gp);
    head_kernel<<<1, 64, 0, stream>>>(gp, b2, Wl, bl, out);
}